// Round 1
// baseline (74.446 us; speedup 1.0000x reference)
//
#include <hip/hip_runtime.h>
#include <math.h>

// Hyp_plus_MLR: logits[b,k] = 2*an_k * asinh( (m.a_hat) * 2/(1-|m|^2) )
// Reduced form: everything along a_hat = z_k/||z_k||; one fp32 GEMM Y.Z^T.
//
// B=2048, D=256, K=128. Block: 16 rows x all 128 k, 256 threads.
// Per-thread: 4 rows (by wave) x 2 k (lane, lane+64).

#define D_DIM 256
#define K_DIM 128
#define BT    16

__global__ __launch_bounds__(256) void hyp_mlr_kernel(
    const float* __restrict__ Y,   // (2048,256) output_before
    const float* __restrict__ Z,   // (128,256)  z_mlr
    const float* __restrict__ R,   // (128,1)    mlr_r
    float* __restrict__ out)       // (2048,128) logits.T
{
  __shared__ float yt[BT][260];       // +4 pad: keeps float4 alignment, breaks bank stride
  __shared__ float zt[K_DIM][68];     // 64-wide d-chunk, +4 pad
  __shared__ float sc_inv_nz[K_DIM];
  __shared__ float sc_ts[K_DIM];
  __shared__ float sc_an2[K_DIM];
  __shared__ float py2[BT][4];
  __shared__ float sy2[BT];

  const int t    = threadIdx.x;
  const int wave = t >> 6;
  const int lane = t & 63;
  const int b0   = blockIdx.x * BT;

  // ---- stage Y tile (coalesced float4) ----
  for (int idx = t; idx < BT * 64; idx += 256) {
    int row = idx >> 6;            // 64 float4 per row
    int j4  = idx & 63;
    float4 v = *(const float4*)(Y + (b0 + row) * D_DIM + j4 * 4);
    *(float4*)&yt[row][j4 * 4] = v;
  }
  __syncthreads();

  // ---- y2 partials (64 threads, 4 per row) ----
  if (t < 64) {
    int row = t >> 2, q = t & 3;
    const float* p = &yt[row][q * 64];
    float s = 0.f;
    #pragma unroll
    for (int j = 0; j < 16; ++j) {
      float4 v = *(const float4*)(p + 4 * j);
      s = fmaf(v.x, v.x, s); s = fmaf(v.y, v.y, s);
      s = fmaf(v.z, v.z, s); s = fmaf(v.w, v.w, s);
    }
    py2[row][q] = s;
  }

  float a00 = 0.f, a01 = 0.f, a02 = 0.f, a03 = 0.f;  // k = lane,    rows 0..3
  float a10 = 0.f, a11 = 0.f, a12 = 0.f, a13 = 0.f;  // k = lane+64, rows 0..3
  float nz2 = 0.f;                                    // thread t<128 owns k=t

  for (int c = 0; c < 4; ++c) {
    __syncthreads();   // protect zt against readers of previous chunk
    // ---- stage Z chunk: z[0..127][c*64 .. c*64+63] ----
    for (int idx = t; idx < K_DIM * 16; idx += 256) {
      int k  = idx >> 4;          // 16 float4 per (row,chunk)
      int j4 = idx & 15;
      float4 v = *(const float4*)(Z + k * D_DIM + c * 64 + j4 * 4);
      *(float4*)&zt[k][j4 * 4] = v;
    }
    __syncthreads();

    // ---- accumulate ||z_k||^2 from the staged chunk (waves 0,1 only) ----
    if (t < K_DIM) {
      const float* p = &zt[t][0];
      #pragma unroll
      for (int j = 0; j < 16; ++j) {
        float4 v = *(const float4*)(p + 4 * j);
        nz2 = fmaf(v.x, v.x, nz2); nz2 = fmaf(v.y, v.y, nz2);
        nz2 = fmaf(v.z, v.z, nz2); nz2 = fmaf(v.w, v.w, nz2);
      }
    }

    // ---- GEMM inner: 4 rows x 2 k per thread over this 64-d chunk ----
    const float* zp0 = &zt[lane][0];
    const float* zp1 = &zt[lane + 64][0];
    const float* y0p = &yt[wave * 4 + 0][c * 64];   // wave-uniform -> LDS broadcast
    const float* y1p = &yt[wave * 4 + 1][c * 64];
    const float* y2p = &yt[wave * 4 + 2][c * 64];
    const float* y3p = &yt[wave * 4 + 3][c * 64];
    #pragma unroll 4
    for (int j = 0; j < 16; ++j) {
      float4 z0 = *(const float4*)(zp0 + 4 * j);
      float4 z1 = *(const float4*)(zp1 + 4 * j);
      float4 v0 = *(const float4*)(y0p + 4 * j);
      float4 v1 = *(const float4*)(y1p + 4 * j);
      float4 v2 = *(const float4*)(y2p + 4 * j);
      float4 v3 = *(const float4*)(y3p + 4 * j);
      a00 = fmaf(v0.x, z0.x, a00); a00 = fmaf(v0.y, z0.y, a00);
      a00 = fmaf(v0.z, z0.z, a00); a00 = fmaf(v0.w, z0.w, a00);
      a01 = fmaf(v1.x, z0.x, a01); a01 = fmaf(v1.y, z0.y, a01);
      a01 = fmaf(v1.z, z0.z, a01); a01 = fmaf(v1.w, z0.w, a01);
      a02 = fmaf(v2.x, z0.x, a02); a02 = fmaf(v2.y, z0.y, a02);
      a02 = fmaf(v2.z, z0.z, a02); a02 = fmaf(v2.w, z0.w, a02);
      a03 = fmaf(v3.x, z0.x, a03); a03 = fmaf(v3.y, z0.y, a03);
      a03 = fmaf(v3.z, z0.z, a03); a03 = fmaf(v3.w, z0.w, a03);
      a10 = fmaf(v0.x, z1.x, a10); a10 = fmaf(v0.y, z1.y, a10);
      a10 = fmaf(v0.z, z1.z, a10); a10 = fmaf(v0.w, z1.w, a10);
      a11 = fmaf(v1.x, z1.x, a11); a11 = fmaf(v1.y, z1.y, a11);
      a11 = fmaf(v1.z, z1.z, a11); a11 = fmaf(v1.w, z1.w, a11);
      a12 = fmaf(v2.x, z1.x, a12); a12 = fmaf(v2.y, z1.y, a12);
      a12 = fmaf(v2.z, z1.z, a12); a12 = fmaf(v2.w, z1.w, a12);
      a13 = fmaf(v3.x, z1.x, a13); a13 = fmaf(v3.y, z1.y, a13);
      a13 = fmaf(v3.z, z1.z, a13); a13 = fmaf(v3.w, z1.w, a13);
    }
  }

  // ---- per-k scalars (threads 0..127, k = t) ----
  if (t < K_DIM) {
    float nz = sqrtf(nz2);
    float r  = R[t];
    float un = fmaxf(fabsf(r) * nz, 1e-15f);   // EPS clamp, matches ref
    float th = tanhf(un);
    float ts = copysignf(th, r);               // sign(r)*tanh(un)
    float ch = coshf(r);
    float an = nz / (ch * ch);                 // ||a|| = ||z||/cosh^2(r)
    sc_inv_nz[t] = 1.f / fmaxf(nz, 1e-30f);
    sc_ts[t]     = ts;
    sc_an2[t]    = 2.f * an;
  }
  if (t < BT) sy2[t] = py2[t][0] + py2[t][1] + py2[t][2] + py2[t][3];
  __syncthreads();

  // ---- epilogue: closed-form hyperbolic MLR per (row, k) ----
  float accs[2][4] = {{a00, a01, a02, a03}, {a10, a11, a12, a13}};
  #pragma unroll
  for (int kk = 0; kk < 2; ++kk) {
    int k = lane + kk * 64;
    float inv_nz = sc_inv_nz[k];
    float ts     = sc_ts[k];
    float an2    = sc_an2[k];
    float x2     = ts * ts;
    #pragma unroll
    for (int rr = 0; rr < 4; ++rr) {
      int row  = wave * 4 + rr;
      float y2 = sy2[row];
      float w  = accs[kk][rr] * inv_nz;        // y . a_hat
      float xy = -ts * w;                       // x . y
      float A   = 1.f + 2.f * xy + y2;
      float Bc  = 1.f - x2;
      float den = 1.f + 2.f * xy + x2 * y2;
      float invden = 1.f / den;
      float mm  = (A * A * x2 + 2.f * A * Bc * xy + Bc * Bc * y2) * invden * invden;
      float lam = 2.f / (1.f - mm);
      float ma  = (Bc * w - A * ts) * invden;  // m . a_hat
      out[(b0 + row) * K_DIM + k] = an2 * asinhf(ma * lam);
    }
  }
}

extern "C" void kernel_launch(void* const* d_in, const int* in_sizes, int n_in,
                              void* d_out, int out_size, void* d_ws, size_t ws_size,
                              hipStream_t stream) {
  const float* Y = (const float*)d_in[0];   // output_before (2048,256)
  const float* Z = (const float*)d_in[1];   // z_mlr (128,256)
  const float* R = (const float*)d_in[2];   // mlr_r (128,1)
  float* out = (float*)d_out;               // (2048,128)
  hipLaunchKernelGGL(hyp_mlr_kernel, dim3(2048 / BT), dim3(256), 0, stream,
                     Y, Z, R, out);
}

// Round 2
// 66.809 us; speedup vs baseline: 1.1143x; 1.1143x over previous
//
#include <hip/hip_runtime.h>
#include <math.h>

// Hyp_plus_MLR closed form: everything reduces along a_hat = z_k/||z_k||.
//   ts = sign(r)*tanh(|r|*||z||), an = ||z||/cosh^2(r), w = (y.z)/||z||
//   xy=-ts*w, x2=ts^2, A=1+2xy+y2, Bc=1-x2, den=1+2xy+x2*y2
//   |m|^2=(A^2 x2+2ABc xy+Bc^2 y2)/den^2, m.a_hat=(Bc w-A ts)/den
//   logit = 2*an*asinh((m.a_hat)*2/(1-|m|^2))
//
// Grid 256 blocks (8 rows each) x 256 threads: wave w owns rows {2w,2w+1},
// thread owns k = {lane, lane+64}. y via wave-uniform (scalar-cache) loads,
// z via LDS (64-d chunks, stride 68 -> 2-way bank aliasing = free).

#define D_DIM 256
#define K_DIM 128
#define ZS    68   // zt row stride (floats): 17 quads -> only 2-way bank alias

__global__ __launch_bounds__(256) void hyp_mlr_kernel(
    const float* __restrict__ Y,   // (2048,256)
    const float* __restrict__ Z,   // (128,256)
    const float* __restrict__ R,   // (128,1)
    float* __restrict__ out)       // (2048,128)
{
  __shared__ float zt[K_DIM * ZS];      // 34.8 KB
  __shared__ float sc_inv_nz[K_DIM];
  __shared__ float sc_ts[K_DIM];
  __shared__ float sc_an2[K_DIM];

  const int t    = threadIdx.x;
  const int lane = t & 63;
  const int wv   = __builtin_amdgcn_readfirstlane(t >> 6);  // provably uniform wave id
  const int row0 = blockIdx.x * 8 + wv * 2;

  // ---- y2 for this wave's two rows (coalesced; also warms L2 for scalar y loads) ----
  const float* yr0 = Y + row0 * D_DIM;
  const float* yr1 = yr0 + D_DIM;
  float4 u0 = *(const float4*)(yr0 + lane * 4);
  float4 u1 = *(const float4*)(yr1 + lane * 4);
  float s0 = u0.x*u0.x + u0.y*u0.y + u0.z*u0.z + u0.w*u0.w;
  float s1 = u1.x*u1.x + u1.y*u1.y + u1.z*u1.z + u1.w*u1.w;
  #pragma unroll
  for (int off = 32; off > 0; off >>= 1) {
    s0 += __shfl_xor(s0, off);
    s1 += __shfl_xor(s1, off);
  }
  const float y2r0 = s0, y2r1 = s1;

  float a00 = 0.f, a01 = 0.f, a10 = 0.f, a11 = 0.f;  // a<row><khalf>
  float nz2 = 0.f;                                    // thread t<128 owns k=t

  const float* zp0 = &zt[lane * ZS];
  const float* zp1 = &zt[(lane + 64) * ZS];

  for (int c = 0; c < 4; ++c) {
    __syncthreads();   // writers vs readers of previous chunk
    // ---- stage Z chunk c: z[0..127][64c .. 64c+63], coalesced float4 ----
    #pragma unroll
    for (int i = 0; i < 8; ++i) {
      int idx = t + i * 256;          // over 128 rows x 16 quads
      int r = idx >> 4, q = idx & 15;
      float4 v = *(const float4*)(Z + r * D_DIM + c * 64 + q * 4);
      *(float4*)&zt[r * ZS + q * 4] = v;
    }
    __syncthreads();

    // ---- ||z_k||^2 from the staged chunk (waves 0,1) ----
    if (t < K_DIM) {
      const float* p = &zt[t * ZS];
      #pragma unroll
      for (int i = 0; i < 16; ++i) {
        float4 v = *(const float4*)(p + 4 * i);
        nz2 = fmaf(v.x, v.x, nz2); nz2 = fmaf(v.y, v.y, nz2);
        nz2 = fmaf(v.z, v.z, nz2); nz2 = fmaf(v.w, v.w, nz2);
      }
    }

    // ---- GEMM: 2 rows x 2 k per thread; y wave-uniform -> scalar loads ----
    const float* y0p = yr0 + c * 64;
    const float* y1p = yr1 + c * 64;
    #pragma unroll
    for (int j = 0; j < 16; ++j) {
      float4 z0 = *(const float4*)(zp0 + 4 * j);
      float4 z1 = *(const float4*)(zp1 + 4 * j);
      float4 y0 = *(const float4*)(y0p + 4 * j);
      float4 y1 = *(const float4*)(y1p + 4 * j);
      a00 = fmaf(y0.x, z0.x, a00); a00 = fmaf(y0.y, z0.y, a00);
      a00 = fmaf(y0.z, z0.z, a00); a00 = fmaf(y0.w, z0.w, a00);
      a01 = fmaf(y0.x, z1.x, a01); a01 = fmaf(y0.y, z1.y, a01);
      a01 = fmaf(y0.z, z1.z, a01); a01 = fmaf(y0.w, z1.w, a01);
      a10 = fmaf(y1.x, z0.x, a10); a10 = fmaf(y1.y, z0.y, a10);
      a10 = fmaf(y1.z, z0.z, a10); a10 = fmaf(y1.w, z0.w, a10);
      a11 = fmaf(y1.x, z1.x, a11); a11 = fmaf(y1.y, z1.y, a11);
      a11 = fmaf(y1.z, z1.z, a11); a11 = fmaf(y1.w, z1.w, a11);
    }
  }

  // ---- per-k scalars (threads 0..127, k = t) ----
  if (t < K_DIM) {
    float nz = sqrtf(nz2);
    float r  = R[t];
    float un = fmaxf(fabsf(r) * nz, 1e-15f);   // EPS clamp, matches ref
    float ts = copysignf(tanhf(un), r);        // sign(r)*tanh(un)
    float ch = coshf(r);
    sc_inv_nz[t] = 1.f / fmaxf(nz, 1e-30f);
    sc_ts[t]     = ts;
    sc_an2[t]    = 2.f * nz / (ch * ch);       // 2*||a||
  }
  __syncthreads();

  // ---- epilogue: closed-form hyperbolic MLR per (row, k) ----
  float acc[2][2] = {{a00, a01}, {a10, a11}};
  #pragma unroll
  for (int kk = 0; kk < 2; ++kk) {
    int k = lane + kk * 64;
    float inv_nz = sc_inv_nz[k];
    float ts     = sc_ts[k];
    float an2    = sc_an2[k];
    float x2     = ts * ts;
    #pragma unroll
    for (int r = 0; r < 2; ++r) {
      float y2 = r ? y2r1 : y2r0;
      float w  = acc[r][kk] * inv_nz;          // y . a_hat
      float xy = -ts * w;
      float A   = 1.f + 2.f * xy + y2;
      float Bc  = 1.f - x2;
      float den = 1.f + 2.f * xy + x2 * y2;
      float invden = 1.f / den;
      float mm  = (A*A*x2 + 2.f*A*Bc*xy + Bc*Bc*y2) * invden * invden;
      float lam = 2.f / (1.f - mm);
      float ma  = (Bc * w - A * ts) * invden;  // m . a_hat
      out[(row0 + r) * K_DIM + k] = an2 * asinhf(ma * lam);
    }
  }
}

extern "C" void kernel_launch(void* const* d_in, const int* in_sizes, int n_in,
                              void* d_out, int out_size, void* d_ws, size_t ws_size,
                              hipStream_t stream) {
  const float* Y = (const float*)d_in[0];
  const float* Z = (const float*)d_in[1];
  const float* R = (const float*)d_in[2];
  float* out = (float*)d_out;
  hipLaunchKernelGGL(hyp_mlr_kernel, dim3(2048 / 8), dim3(256), 0, stream,
                     Y, Z, R, out);
}